// Round 20
// baseline (24.287 us; speedup 1.0000x reference)
//
#include <hip/hip_runtime.h>

// TransformerBlockQuantum: B=16384, S=8, E=8, H=8 (dk=1), NW=8, FFN=512.
// R20 = R17 structure + front weights in VGPRs (f16 half2, ~160 regs,
// loaded once per wave via wave-uniform global_load_dwordx4) -> all front
// matvecs are v_dot2 on register operands, ZERO DS reads on the matvec path.
// Attention: R14 kv-f16-pack, per-head gather (bounds register liveness).
// Biases + FFN epilogue params in small LDS array. FFN: R17's 4-tile MFMA
// with LDS-staged fragments. launch_bounds(256,2) -> <=256 VGPR, 8 waves/CU.

typedef __fp16 half2v __attribute__((ext_vector_type(2)));
typedef __fp16 half4  __attribute__((ext_vector_type(4)));
typedef float  float4v __attribute__((ext_vector_type(4)));

#define SWZ16(v) __int_as_float(__builtin_amdgcn_ds_swizzle(__float_as_int(v), (16 << 10) | 0x1F))
#define SWZI_(v, dlit) __builtin_amdgcn_ds_swizzle((v), ((dlit) << 5) | 0x18)
#define GATHERJ8(dst, src)                                  \
    do {                                                    \
        dst[0] = SWZI_(src, 0); dst[1] = SWZI_(src, 1);     \
        dst[2] = SWZI_(src, 2); dst[3] = SWZI_(src, 3);     \
        dst[4] = SWZI_(src, 4); dst[5] = SWZI_(src, 5);     \
        dst[6] = SWZI_(src, 6); dst[7] = SWZI_(src, 7);     \
    } while (0)
// 4-term f16 dot2 chain: sum_p dot2(xv[p], wr[p])
#define FD4(xv, wr)                                                        \
    __builtin_amdgcn_fdot2((xv)[3], (wr)[3],                               \
    __builtin_amdgcn_fdot2((xv)[2], (wr)[2],                               \
    __builtin_amdgcn_fdot2((xv)[1], (wr)[1],                               \
    __builtin_amdgcn_fdot2((xv)[0], (wr)[0], 0.f, false), false), false), false)

// float offsets in wl[] (all 16B-aligned)
#define O_IPB 0
#define O_OPB 24
#define O_CB  32
#define O_RXA 40
#define O_G1  48
#define O_B1  56
#define O_RXF 64
#define O_L2B 72
#define O_G2  80
#define O_B2  88

__global__ __launch_bounds__(256, 2) void tbq_fused(
    const float* __restrict__ x,
    const float* __restrict__ ipw, const float* __restrict__ ipb,
    const float* __restrict__ opw, const float* __restrict__ opb,
    const float* __restrict__ rxa,
    const float* __restrict__ cw,  const float* __restrict__ cb,
    const float* __restrict__ g1,  const float* __restrict__ b1,
    const float* __restrict__ rxf,
    const float* __restrict__ l1w, const float* __restrict__ l1b,
    const float* __restrict__ l2w, const float* __restrict__ l2b,
    const float* __restrict__ g2,  const float* __restrict__ b2,
    float* __restrict__ out)
{
    __shared__ half4 a1l[2048];                       // 16KB
    __shared__ half4 a2l[2048];                       // 16KB
    __shared__ __align__(16) float lds_hh[256][12];   // 12KB
    __shared__ __align__(16) float wl[96];            // biases/LN/rx params

    const int tid = threadIdx.x;
    const int l   = tid & 63;
    const int wv  = tid >> 6;
    const int tok = blockIdx.x * 256 + tid;
    const int base = tok * 8;

    // ---- issue x load first ----
    const float4* px = reinterpret_cast<const float4*>(x + base);
    float4 xa = px[0], xb = px[1];

    // ---- front weights -> VGPRs as f16 half2 (wave-uniform loads) ----
    half2v wip[24][4], wop[8][4], wcw[8][4];
    {
        const float4* g = reinterpret_cast<const float4*>(ipw);
        #pragma unroll
        for (int r = 0; r < 24; ++r) {
            float4 w0 = g[r * 2], w1 = g[r * 2 + 1];
            wip[r][0] = __builtin_amdgcn_cvt_pkrtz(w0.x, w0.y);
            wip[r][1] = __builtin_amdgcn_cvt_pkrtz(w0.z, w0.w);
            wip[r][2] = __builtin_amdgcn_cvt_pkrtz(w1.x, w1.y);
            wip[r][3] = __builtin_amdgcn_cvt_pkrtz(w1.z, w1.w);
        }
        const float4* go = reinterpret_cast<const float4*>(opw);
        const float4* gc = reinterpret_cast<const float4*>(cw);
        #pragma unroll
        for (int r = 0; r < 8; ++r) {
            float4 w0 = go[r * 2], w1 = go[r * 2 + 1];
            wop[r][0] = __builtin_amdgcn_cvt_pkrtz(w0.x, w0.y);
            wop[r][1] = __builtin_amdgcn_cvt_pkrtz(w0.z, w0.w);
            wop[r][2] = __builtin_amdgcn_cvt_pkrtz(w1.x, w1.y);
            wop[r][3] = __builtin_amdgcn_cvt_pkrtz(w1.z, w1.w);
            float4 c0 = gc[r * 2], c1 = gc[r * 2 + 1];
            wcw[r][0] = __builtin_amdgcn_cvt_pkrtz(c0.x, c0.y);
            wcw[r][1] = __builtin_amdgcn_cvt_pkrtz(c0.z, c0.w);
            wcw[r][2] = __builtin_amdgcn_cvt_pkrtz(c1.x, c1.y);
            wcw[r][3] = __builtin_amdgcn_cvt_pkrtz(c1.z, c1.w);
        }
    }

    // ---- stage biases/params into LDS ----
    if (tid < 24)      wl[O_IPB + tid]        = ipb[tid];
    else if (tid < 32) wl[O_OPB + (tid - 24)] = opb[tid - 24];
    else if (tid < 40) wl[O_CB  + (tid - 32)] = cb[tid - 32];
    else if (tid < 48) wl[O_RXA + (tid - 40)] = rxa[tid - 40];
    else if (tid < 56) wl[O_G1  + (tid - 48)] = g1[tid - 48];
    else if (tid < 64) wl[O_B1  + (tid - 56)] = b1[tid - 56];
    else if (tid < 72) wl[O_RXF + (tid - 64)] = rxf[tid - 64];
    else if (tid < 80) wl[O_L2B + (tid - 72)] = l2b[tid - 72];
    else if (tid < 88) wl[O_G2  + (tid - 80)] = g2[tid - 80];
    else if (tid < 96) wl[O_B2  + (tid - 88)] = b2[tid - 88];

    // ---- cooperative fragment pack: f32 weights -> f16 frags in LDS ----
    const half4 zh = {(__fp16)0.f, (__fp16)0.f, (__fp16)0.f, (__fp16)0.f};
    #pragma unroll 1
    for (int i = 0; i < 8; ++i) {
        const int u  = tid + i * 256;
        const int nf = u >> 6, ll = u & 63;
        const int mm = ll & 15, kk0 = (ll >> 4) * 4;
        half4 r1 = zh;
        if (ll < 32) {
            float4 w = *reinterpret_cast<const float4*>(l1w + (nf * 16 + mm) * 8 + kk0);
            half2v c0 = __builtin_amdgcn_cvt_pkrtz(w.x, w.y);
            half2v c1 = __builtin_amdgcn_cvt_pkrtz(w.z, w.w);
            r1.x = c0.x; r1.y = c0.y; r1.z = c1.x; r1.w = c1.y;
        } else if (ll < 48) {
            r1.x = (__fp16)l1b[nf * 16 + mm];
        }
        a1l[u] = r1;
        half4 r2 = zh;
        if (mm < 8) {
            float4 w = *reinterpret_cast<const float4*>(l2w + mm * 512 + nf * 16 + kk0);
            half2v c0 = __builtin_amdgcn_cvt_pkrtz(w.x, w.y);
            half2v c1 = __builtin_amdgcn_cvt_pkrtz(w.z, w.w);
            r2.x = c0.x; r2.y = c0.y; r2.z = c1.x; r2.w = c1.y;
        }
        a2l[u] = r2;
    }
    __syncthreads();

    // ---- front: all matvecs on register weights via v_dot2 ----
    float xr[8];
    xr[0] = xa.x; xr[1] = xa.y; xr[2] = xa.z; xr[3] = xa.w;
    xr[4] = xb.x; xr[5] = xb.y; xr[6] = xb.z; xr[7] = xb.w;
    half2v xh[4];
    xh[0] = __builtin_amdgcn_cvt_pkrtz(xr[0], xr[1]);
    xh[1] = __builtin_amdgcn_cvt_pkrtz(xr[2], xr[3]);
    xh[2] = __builtin_amdgcn_cvt_pkrtz(xr[4], xr[5]);
    xh[3] = __builtin_amdgcn_cvt_pkrtz(xr[6], xr[7]);

    float q[8];
    int kvp[8];
    #pragma unroll
    for (int e = 0; e < 8; ++e) {
        q[e]       = wl[O_IPB + e]      + FD4(xh, wip[e]);
        float ke   = wl[O_IPB + 8 + e]  + FD4(xh, wip[8 + e]);
        float ve   = wl[O_IPB + 16 + e] + FD4(xh, wip[16 + e]);
        half2v pk  = __builtin_amdgcn_cvt_pkrtz(ke, ve);
        kvp[e] = __builtin_bit_cast(int, pk);
    }

    // attention: per-head kv gather; softmax w/o max-sub; exp2 prefold
    float orow[8];
    #pragma unroll
    for (int h = 0; h < 8; ++h) {
        int kvg[8];
        GATHERJ8(kvg, kvp[h]);
        const float qh2 = q[h] * 1.44269504f;
        float sum = 0.f, ov = 0.f;
        #pragma unroll
        for (int j = 0; j < 8; ++j) {
            half2v kv = __builtin_bit_cast(half2v, kvg[j]);
            float p = exp2f(qh2 * (float)kv.x);
            sum += p;
            ov = fmaf(p, (float)kv.y, ov);
        }
        orow[h] = ov * __builtin_amdgcn_rcpf(sum);
    }

    half2v oh[4];
    oh[0] = __builtin_amdgcn_cvt_pkrtz(orow[0], orow[1]);
    oh[1] = __builtin_amdgcn_cvt_pkrtz(orow[2], orow[3]);
    oh[2] = __builtin_amdgcn_cvt_pkrtz(orow[4], orow[5]);
    oh[3] = __builtin_amdgcn_cvt_pkrtz(orow[6], orow[7]);
    float ao[8];
    #pragma unroll
    for (int e = 0; e < 8; ++e) ao[e] = wl[O_OPB + e] + FD4(oh, wop[e]);

    float c[8];
    #pragma unroll
    for (int w = 0; w < 8; ++w) c[w] = __cosf(ao[w] + wl[O_RXA + w]);
    float z[8];
    {
        float run = c[0];
        #pragma unroll
        for (int w = 1; w < 8; ++w) { run *= c[w]; z[w] = run; }
        float s17 = c[1];
        #pragma unroll
        for (int w = 2; w < 8; ++w) s17 *= c[w];
        z[0] = s17;
    }

    half2v zp[4];
    zp[0] = __builtin_amdgcn_cvt_pkrtz(z[0], z[1]);
    zp[1] = __builtin_amdgcn_cvt_pkrtz(z[2], z[3]);
    zp[2] = __builtin_amdgcn_cvt_pkrtz(z[4], z[5]);
    zp[3] = __builtin_amdgcn_cvt_pkrtz(z[6], z[7]);
    float saq[8];
    #pragma unroll
    for (int e = 0; e < 8; ++e) saq[e] = ao[e] + wl[O_CB + e] + FD4(zp, wcw[e]);

    half2v sp[4];
    sp[0] = __builtin_amdgcn_cvt_pkrtz(saq[0], saq[1]);
    sp[1] = __builtin_amdgcn_cvt_pkrtz(saq[2], saq[3]);
    sp[2] = __builtin_amdgcn_cvt_pkrtz(saq[4], saq[5]);
    sp[3] = __builtin_amdgcn_cvt_pkrtz(saq[6], saq[7]);
    float at[8];
    #pragma unroll
    for (int e = 0; e < 8; ++e) at[e] = wl[O_CB + e] + FD4(sp, wcw[e]);

    float r[8]; float mean = 0.f;
    #pragma unroll
    for (int e = 0; e < 8; ++e) { r[e] = xr[e] + at[e]; mean += r[e]; }
    mean *= 0.125f;
    float var = 0.f;
    #pragma unroll
    for (int e = 0; e < 8; ++e) { float d = r[e] - mean; var = fmaf(d, d, var); }
    var *= 0.125f;
    float rs = __builtin_amdgcn_rsqf(var + 1e-5f);
    {
        float4 hlo, hhi;
        hlo.x = fmaf((r[0] - mean) * rs, wl[O_G1 + 0], wl[O_B1 + 0]);
        hlo.y = fmaf((r[1] - mean) * rs, wl[O_G1 + 1], wl[O_B1 + 1]);
        hlo.z = fmaf((r[2] - mean) * rs, wl[O_G1 + 2], wl[O_B1 + 2]);
        hlo.w = fmaf((r[3] - mean) * rs, wl[O_G1 + 3], wl[O_B1 + 3]);
        hhi.x = fmaf((r[4] - mean) * rs, wl[O_G1 + 4], wl[O_B1 + 4]);
        hhi.y = fmaf((r[5] - mean) * rs, wl[O_G1 + 5], wl[O_B1 + 5]);
        hhi.z = fmaf((r[6] - mean) * rs, wl[O_G1 + 6], wl[O_B1 + 6]);
        hhi.w = fmaf((r[7] - mean) * rs, wl[O_G1 + 7], wl[O_B1 + 7]);
        *reinterpret_cast<float4*>(&lds_hh[tid][0]) = hlo;
        *reinterpret_cast<float4*>(&lds_hh[tid][4]) = hhi;
    }
    // No barrier: wave's FFN reads only its own 64 lds_hh rows (lgkm-ordered).

    // ---- FFN: wave owns 64 tokens = 4 tiles ----
    const int m  = l & 15;
    const int kg = (l >> 4) * 4;
    const int wtok = wv * 64;

    float4 h40 = make_float4(0.f, 0.f, 0.f, 0.f), h41 = h40, h42 = h40, h43 = h40;
    half4 bz0 = zh, bz1 = zh, bz2 = zh, bz3 = zh;
    if (l < 32) {
        h40 = *reinterpret_cast<const float4*>(&lds_hh[wtok + m][kg]);
        h41 = *reinterpret_cast<const float4*>(&lds_hh[wtok + 16 + m][kg]);
        h42 = *reinterpret_cast<const float4*>(&lds_hh[wtok + 32 + m][kg]);
        h43 = *reinterpret_cast<const float4*>(&lds_hh[wtok + 48 + m][kg]);
        float4 rx4 = *reinterpret_cast<const float4*>(&wl[O_RXF + kg]);
        half2v c0, c1;
        c0 = __builtin_amdgcn_cvt_pkrtz(__cosf(h40.x + rx4.x), __cosf(h40.y + rx4.y));
        c1 = __builtin_amdgcn_cvt_pkrtz(__cosf(h40.z + rx4.z), __cosf(h40.w + rx4.w));
        bz0.x = c0.x; bz0.y = c0.y; bz0.z = c1.x; bz0.w = c1.y;
        c0 = __builtin_amdgcn_cvt_pkrtz(__cosf(h41.x + rx4.x), __cosf(h41.y + rx4.y));
        c1 = __builtin_amdgcn_cvt_pkrtz(__cosf(h41.z + rx4.z), __cosf(h41.w + rx4.w));
        bz1.x = c0.x; bz1.y = c0.y; bz1.z = c1.x; bz1.w = c1.y;
        c0 = __builtin_amdgcn_cvt_pkrtz(__cosf(h42.x + rx4.x), __cosf(h42.y + rx4.y));
        c1 = __builtin_amdgcn_cvt_pkrtz(__cosf(h42.z + rx4.z), __cosf(h42.w + rx4.w));
        bz2.x = c0.x; bz2.y = c0.y; bz2.z = c1.x; bz2.w = c1.y;
        c0 = __builtin_amdgcn_cvt_pkrtz(__cosf(h43.x + rx4.x), __cosf(h43.y + rx4.y));
        c1 = __builtin_amdgcn_cvt_pkrtz(__cosf(h43.z + rx4.z), __cosf(h43.w + rx4.w));
        bz3.x = c0.x; bz3.y = c0.y; bz3.z = c1.x; bz3.w = c1.y;
    } else if (l < 48) {
        bz0.x = (__fp16)1.f; bz1.x = (__fp16)1.f;
        bz2.x = (__fp16)1.f; bz3.x = (__fp16)1.f;
    }

    const float4v zero4 = {0.f, 0.f, 0.f, 0.f};
    float4v acc0 = zero4, acc1 = zero4, acc2 = zero4, acc3 = zero4;
    #pragma unroll 2
    for (int nf = 0; nf < 32; ++nf) {
        half4 a1f = a1l[nf * 64 + l];
        half4 a2f = a2l[nf * 64 + l];
        float4v d0 = __builtin_amdgcn_mfma_f32_16x16x16f16(a1f, bz0, zero4, 0, 0, 0);
        float4v d1 = __builtin_amdgcn_mfma_f32_16x16x16f16(a1f, bz1, zero4, 0, 0, 0);
        float4v d2 = __builtin_amdgcn_mfma_f32_16x16x16f16(a1f, bz2, zero4, 0, 0, 0);
        float4v d3 = __builtin_amdgcn_mfma_f32_16x16x16f16(a1f, bz3, zero4, 0, 0, 0);
        half4 bu0, bu1, bu2, bu3;
        {
            half2v p0 = __builtin_amdgcn_cvt_pkrtz(d0.x, d0.y);
            half2v p1 = __builtin_amdgcn_cvt_pkrtz(d0.z, d0.w);
            bu0.x = p0.x; bu0.y = p0.y; bu0.z = p1.x; bu0.w = p1.y;
            p0 = __builtin_amdgcn_cvt_pkrtz(d1.x, d1.y);
            p1 = __builtin_amdgcn_cvt_pkrtz(d1.z, d1.w);
            bu1.x = p0.x; bu1.y = p0.y; bu1.z = p1.x; bu1.w = p1.y;
            p0 = __builtin_amdgcn_cvt_pkrtz(d2.x, d2.y);
            p1 = __builtin_amdgcn_cvt_pkrtz(d2.z, d2.w);
            bu2.x = p0.x; bu2.y = p0.y; bu2.z = p1.x; bu2.w = p1.y;
            p0 = __builtin_amdgcn_cvt_pkrtz(d3.x, d3.y);
            p1 = __builtin_amdgcn_cvt_pkrtz(d3.z, d3.w);
            bu3.x = p0.x; bu3.y = p0.y; bu3.z = p1.x; bu3.w = p1.y;
        }
        bu0 = __builtin_elementwise_max(bu0, zh);
        bu1 = __builtin_elementwise_max(bu1, zh);
        bu2 = __builtin_elementwise_max(bu2, zh);
        bu3 = __builtin_elementwise_max(bu3, zh);
        acc0 = __builtin_amdgcn_mfma_f32_16x16x16f16(a2f, bu0, acc0, 0, 0, 0);
        acc1 = __builtin_amdgcn_mfma_f32_16x16x16f16(a2f, bu1, acc1, 0, 0, 0);
        acc2 = __builtin_amdgcn_mfma_f32_16x16x16f16(a2f, bu2, acc2, 0, 0, 0);
        acc3 = __builtin_amdgcn_mfma_f32_16x16x16f16(a2f, bu3, acc3, 0, 0, 0);
    }

    // ---- epilogue: residual + LN2 + store (lanes 0-31, 4 tiles) ----
    if (l < 32) {
        const float4 lb4 = *reinterpret_cast<const float4*>(&wl[O_L2B + kg]);
        const float4 g4  = *reinterpret_cast<const float4*>(&wl[O_G2 + kg]);
        const float4 bb4 = *reinterpret_cast<const float4*>(&wl[O_B2 + kg]);
        const int obase = blockIdx.x * 256 + wtok;

        #pragma unroll
        for (int tt = 0; tt < 4; ++tt) {
            float4v acc = (tt == 0) ? acc0 : (tt == 1) ? acc1 : (tt == 2) ? acc2 : acc3;
            float4 h4   = (tt == 0) ? h40  : (tt == 1) ? h41  : (tt == 2) ? h42  : h43;
            float r2[4];
            r2[0] = h4.x + acc.x + lb4.x;
            r2[1] = h4.y + acc.y + lb4.y;
            r2[2] = h4.z + acc.z + lb4.z;
            r2[3] = h4.w + acc.w + lb4.w;
            float part = ((r2[0] + r2[1]) + (r2[2] + r2[3]));
            float mean2 = (part + SWZ16(part)) * 0.125f;
            float d0 = r2[0] - mean2, d1_ = r2[1] - mean2,
                  d2 = r2[2] - mean2, d3 = r2[3] - mean2;
            float vp = ((d0 * d0 + d1_ * d1_) + (d2 * d2 + d3 * d3));
            float rs2 = __builtin_amdgcn_rsqf((vp + SWZ16(vp)) * 0.125f + 1e-5f);
            float4 o;
            o.x = fmaf(d0 * rs2, g4.x, bb4.x);
            o.y = fmaf(d1_ * rs2, g4.y, bb4.y);
            o.z = fmaf(d2 * rs2, g4.z, bb4.z);
            o.w = fmaf(d3 * rs2, g4.w, bb4.w);
            *reinterpret_cast<float4*>(out + (obase + tt * 16 + m) * 8 + kg) = o;
        }
    }
}

extern "C" void kernel_launch(void* const* d_in, const int* in_sizes, int n_in,
                              void* d_out, int out_size, void* d_ws, size_t ws_size,
                              hipStream_t stream) {
    const float* x   = (const float*)d_in[0];
    const float* ipw = (const float*)d_in[1];
    const float* ipb = (const float*)d_in[2];
    const float* opw = (const float*)d_in[3];
    const float* opb = (const float*)d_in[4];
    const float* rxa = (const float*)d_in[5];
    const float* cw  = (const float*)d_in[6];
    const float* cb  = (const float*)d_in[7];
    const float* g1  = (const float*)d_in[8];
    const float* b1  = (const float*)d_in[9];
    const float* rxf = (const float*)d_in[10];
    const float* l1w = (const float*)d_in[11];
    const float* l1b = (const float*)d_in[12];
    const float* l2w = (const float*)d_in[13];
    const float* l2b = (const float*)d_in[14];
    const float* g2  = (const float*)d_in[15];
    const float* b2  = (const float*)d_in[16];
    float* out = (float*)d_out;

    const int tokens = 16384 * 8;               // 131072
    tbq_fused<<<dim3(tokens / 256), dim3(256), 0, stream>>>(
        x, ipw, ipb, opw, opb, rxa, cw, cb, g1, b1, rxf,
        l1w, l1b, l2w, l2b, g2, b2, out);
}

// Round 21
// 21.278 us; speedup vs baseline: 1.1414x; 1.1414x over previous
//
#include <hip/hip_runtime.h>

// TransformerBlockQuantum: B=16384, S=8, E=8, H=8 (dk=1), NW=8, FFN=512.
// R21: FULL-MFMA pipeline. Wave = 16 tokens = one 16x16 tile chain:
//   QKV: 3 MFMAs (A=W+bias k=8 row, B=x^T) -> D[m=row][n=tok]
//   attention: lane g=(l>>4)<2 holds 4 heads (rows 4g+r) of token n=l&15;
//     kv f16-packed, j-gather = (j<<5)|0x18 swizzle (same-batch broadcast)
//   out_proj/combine1/combine2: D packs IN-PLACE into next B-fragment
//   ring/LN1: one xor-16 exchange (g=0 <-> g=1)
//   zf packs in-place into FFN B-fragment -> 32-iter MFMA FFN -> LN2 -> store
// Block 512 thr = 8 waves = 128 tokens; grid 1024; LDS ~35KB (fragments +
// 5 front A-frags + params). 8192 waves total (4x R17). No lds_hh.

typedef __fp16 half2v __attribute__((ext_vector_type(2)));
typedef __fp16 half4  __attribute__((ext_vector_type(4)));
typedef float  float4v __attribute__((ext_vector_type(4)));

#define SWZ16(v) __int_as_float(__builtin_amdgcn_ds_swizzle(__float_as_int(v), (16 << 10) | 0x1F))
#define SWZI_(v, dlit) __builtin_amdgcn_ds_swizzle((v), ((dlit) << 5) | 0x18)
#define GATHERJ8(dst, src)                                  \
    do {                                                    \
        dst[0] = SWZI_(src, 0); dst[1] = SWZI_(src, 1);     \
        dst[2] = SWZI_(src, 2); dst[3] = SWZI_(src, 3);     \
        dst[4] = SWZI_(src, 4); dst[5] = SWZI_(src, 5);     \
        dst[6] = SWZI_(src, 6); dst[7] = SWZI_(src, 7);     \
    } while (0)

// wl float offsets (16-float slots, zero-padded)
#define O_RXA 0
#define O_G1  16
#define O_B1  32
#define O_RXF 48
#define O_L2B 64
#define O_G2  80
#define O_B2  96

__global__ __launch_bounds__(512, 2) void tbq_fused(
    const float* __restrict__ x,
    const float* __restrict__ ipw, const float* __restrict__ ipb,
    const float* __restrict__ opw, const float* __restrict__ opb,
    const float* __restrict__ rxa,
    const float* __restrict__ cw,  const float* __restrict__ cb,
    const float* __restrict__ g1,  const float* __restrict__ b1,
    const float* __restrict__ rxf,
    const float* __restrict__ l1w, const float* __restrict__ l1b,
    const float* __restrict__ l2w, const float* __restrict__ l2b,
    const float* __restrict__ g2,  const float* __restrict__ b2,
    float* __restrict__ out)
{
    __shared__ half4 a1l[2048];                 // 16KB FFN lin1 frags
    __shared__ half4 a2l[2048];                 // 16KB FFN lin2 frags
    __shared__ half4 frontA[320];               // 2.5KB Wq,Wk,Wv,Wo,Wc frags
    __shared__ __align__(16) float wl[112];     // params, 16-float slots

    const int tid = threadIdx.x;
    const int l   = tid & 63;
    const int wv  = tid >> 6;                   // 0..7
    const int n   = l & 15;                     // token in tile
    const int g   = l >> 4;                     // row group (0..3)
    const int k0  = g * 4;
    const int gtok = blockIdx.x * 128 + wv * 16;

    // ---- x load early (B-operand source: x^T) ----
    float4 xw = make_float4(0.f, 0.f, 0.f, 0.f);
    if (g < 2) xw = *reinterpret_cast<const float4*>(x + (gtok + n) * 8 + k0);

    const half4 zh = {(__fp16)0.f, (__fp16)0.f, (__fp16)0.f, (__fp16)0.f};

    // ---- pack: front A-frags (bias at k==8), params, FFN frags ----
    if (tid < 320) {
        const int t = tid >> 6, ll = tid & 63;
        const int m = ll & 15, kk0 = (ll >> 4) * 4;
        half4 r = zh;
        if (m < 8) {
            const float* Wp = (t == 0) ? ipw : (t == 1) ? ipw + 64 :
                              (t == 2) ? ipw + 128 : (t == 3) ? opw : cw;
            const float* Bp = (t == 0) ? ipb : (t == 1) ? ipb + 8 :
                              (t == 2) ? ipb + 16 : (t == 3) ? opb : cb;
            #pragma unroll
            for (int j = 0; j < 4; ++j) {
                int k = kk0 + j;
                float v = (k < 8) ? Wp[m * 8 + k] : ((k == 8) ? Bp[m] : 0.f);
                r[j] = (__fp16)v;
            }
        }
        frontA[tid] = r;
    } else if (tid < 432) {
        const int p = (tid - 320) >> 4, i = (tid - 320) & 15;
        float v = 0.f;
        if (i < 8) {
            v = (p == 0) ? rxa[i] : (p == 1) ? g1[i] : (p == 2) ? b1[i] :
                (p == 3) ? rxf[i] : (p == 4) ? l2b[i] : (p == 5) ? g2[i] : b2[i];
        }
        wl[p * 16 + i] = v;
    }
    #pragma unroll 1
    for (int i = 0; i < 4; ++i) {
        const int u  = tid + i * 512;
        const int nf = u >> 6, ll = u & 63;
        const int mm = ll & 15, kk0 = (ll >> 4) * 4;
        half4 r1 = zh;
        if (ll < 32) {
            float4 w = *reinterpret_cast<const float4*>(l1w + (nf * 16 + mm) * 8 + kk0);
            half2v c0 = __builtin_amdgcn_cvt_pkrtz(w.x, w.y);
            half2v c1 = __builtin_amdgcn_cvt_pkrtz(w.z, w.w);
            r1.x = c0.x; r1.y = c0.y; r1.z = c1.x; r1.w = c1.y;
        } else if (ll < 48) {
            r1.x = (__fp16)l1b[nf * 16 + mm];
        }
        a1l[u] = r1;
        half4 r2 = zh;
        if (mm < 8) {
            float4 w = *reinterpret_cast<const float4*>(l2w + mm * 512 + nf * 16 + kk0);
            half2v c0 = __builtin_amdgcn_cvt_pkrtz(w.x, w.y);
            half2v c1 = __builtin_amdgcn_cvt_pkrtz(w.z, w.w);
            r2.x = c0.x; r2.y = c0.y; r2.z = c1.x; r2.w = c1.y;
        }
        a2l[u] = r2;
    }
    __syncthreads();

    // ---- B-fragment of x (k=embed, n=token); bias row k==8 = 1 ----
    half4 bx = zh;
    if (g < 2) {
        half2v p0 = __builtin_amdgcn_cvt_pkrtz(xw.x, xw.y);
        half2v p1 = __builtin_amdgcn_cvt_pkrtz(xw.z, xw.w);
        bx.x = p0.x; bx.y = p0.y; bx.z = p1.x; bx.w = p1.y;
    } else if (g == 2) bx.x = (__fp16)1.f;

    half4 Aq = frontA[l],       Ak = frontA[64 + l], Av = frontA[128 + l];
    half4 Ao = frontA[192 + l], Ac = frontA[256 + l];

    const float4v zero4 = {0.f, 0.f, 0.f, 0.f};
    float4v qf = __builtin_amdgcn_mfma_f32_16x16x16f16(Aq, bx, zero4, 0, 0, 0);
    float4v kf = __builtin_amdgcn_mfma_f32_16x16x16f16(Ak, bx, zero4, 0, 0, 0);
    float4v vf = __builtin_amdgcn_mfma_f32_16x16x16f16(Av, bx, zero4, 0, 0, 0);

    // ---- attention: lane holds heads 4g+r of token n; j-gather in batch ----
    float orow[4];
    #pragma unroll
    for (int r = 0; r < 4; ++r) {
        half2v pk = __builtin_amdgcn_cvt_pkrtz(kf[r], vf[r]);
        int kvp = __builtin_bit_cast(int, pk);
        int kvg[8];
        GATHERJ8(kvg, kvp);
        const float qh2 = qf[r] * 1.44269504f;
        float sum = 0.f, ov = 0.f;
        #pragma unroll
        for (int j = 0; j < 8; ++j) {
            half2v kv = __builtin_bit_cast(half2v, kvg[j]);
            float p = exp2f(qh2 * (float)kv.x);
            sum += p;
            ov = fmaf(p, (float)kv.y, ov);
        }
        orow[r] = ov * __builtin_amdgcn_rcpf(sum);
    }

    // ---- out_proj: orow packs IN-PLACE to B ----
    half4 bo = zh;
    if (g < 2) {
        half2v p0 = __builtin_amdgcn_cvt_pkrtz(orow[0], orow[1]);
        half2v p1 = __builtin_amdgcn_cvt_pkrtz(orow[2], orow[3]);
        bo.x = p0.x; bo.y = p0.y; bo.z = p1.x; bo.w = p1.y;
    } else if (g == 2) bo.x = (__fp16)1.f;
    float4v aof = __builtin_amdgcn_mfma_f32_16x16x16f16(Ao, bo, zero4, 0, 0, 0);

    // ---- quantum ring: c on own 4 wires, xor-16 exchange, full z ----
    const float4 rxa4 = *reinterpret_cast<const float4*>(&wl[O_RXA + k0]);
    float cx0 = __cosf(aof[0] + rxa4.x), cx1 = __cosf(aof[1] + rxa4.y);
    float cx2 = __cosf(aof[2] + rxa4.z), cx3 = __cosf(aof[3] + rxa4.w);
    float ct0 = SWZ16(cx0), ct1 = SWZ16(cx1), ct2 = SWZ16(cx2), ct3 = SWZ16(cx3);
    const bool sel = (g == 0);
    float cc[8];
    cc[0] = sel ? cx0 : ct0; cc[1] = sel ? cx1 : ct1;
    cc[2] = sel ? cx2 : ct2; cc[3] = sel ? cx3 : ct3;
    cc[4] = sel ? ct0 : cx0; cc[5] = sel ? ct1 : cx1;
    cc[6] = sel ? ct2 : cx2; cc[7] = sel ? ct3 : cx3;
    float z8[8];
    {
        float run = cc[0];
        #pragma unroll
        for (int w = 1; w < 8; ++w) { run *= cc[w]; z8[w] = run; }
        float s17 = cc[1];
        #pragma unroll
        for (int w = 2; w < 8; ++w) s17 *= cc[w];
        z8[0] = s17;
    }

    // ---- combine1: z packs in-place (g picks own half) ----
    float zs0 = sel ? z8[0] : z8[4], zs1 = sel ? z8[1] : z8[5];
    float zs2 = sel ? z8[2] : z8[6], zs3 = sel ? z8[3] : z8[7];
    half4 bz1 = zh;
    if (g < 2) {
        half2v p0 = __builtin_amdgcn_cvt_pkrtz(zs0, zs1);
        half2v p1 = __builtin_amdgcn_cvt_pkrtz(zs2, zs3);
        bz1.x = p0.x; bz1.y = p0.y; bz1.z = p1.x; bz1.w = p1.y;
    } else if (g == 2) bz1.x = (__fp16)1.f;
    float4v qo = __builtin_amdgcn_mfma_f32_16x16x16f16(Ac, bz1, zero4, 0, 0, 0);
    float4v saqf = aof + qo;

    // ---- combine2: saq packs in-place ----
    half4 bs = zh;
    if (g < 2) {
        half2v p0 = __builtin_amdgcn_cvt_pkrtz(saqf[0], saqf[1]);
        half2v p1 = __builtin_amdgcn_cvt_pkrtz(saqf[2], saqf[3]);
        bs.x = p0.x; bs.y = p0.y; bs.z = p1.x; bs.w = p1.y;
    } else if (g == 2) bs.x = (__fp16)1.f;
    float4v atf = __builtin_amdgcn_mfma_f32_16x16x16f16(Ac, bs, zero4, 0, 0, 0);

    // ---- LayerNorm1 (xor-16 reductions across g=0/1) ----
    float r10 = xw.x + atf[0], r11 = xw.y + atf[1];
    float r12 = xw.z + atf[2], r13 = xw.w + atf[3];
    float s4 = (r10 + r11) + (r12 + r13);
    float mean = (s4 + SWZ16(s4)) * 0.125f;
    float dv0 = r10 - mean, dv1 = r11 - mean, dv2 = r12 - mean, dv3 = r13 - mean;
    float vq = (dv0 * dv0 + dv1 * dv1) + (dv2 * dv2 + dv3 * dv3);
    float var = (vq + SWZ16(vq)) * 0.125f;
    float rs = __builtin_amdgcn_rsqf(var + 1e-5f);
    const float4 g14 = *reinterpret_cast<const float4*>(&wl[O_G1 + k0]);
    const float4 b14 = *reinterpret_cast<const float4*>(&wl[O_B1 + k0]);
    float hh0 = fmaf(dv0 * rs, g14.x, b14.x);
    float hh1 = fmaf(dv1 * rs, g14.y, b14.y);
    float hh2 = fmaf(dv2 * rs, g14.z, b14.z);
    float hh3 = fmaf(dv3 * rs, g14.w, b14.w);

    // ---- zf packs in-place into FFN B-fragment ----
    const float4 rxf4 = *reinterpret_cast<const float4*>(&wl[O_RXF + k0]);
    half4 bz = zh;
    if (g < 2) {
        half2v p0 = __builtin_amdgcn_cvt_pkrtz(__cosf(hh0 + rxf4.x), __cosf(hh1 + rxf4.y));
        half2v p1 = __builtin_amdgcn_cvt_pkrtz(__cosf(hh2 + rxf4.z), __cosf(hh3 + rxf4.w));
        bz.x = p0.x; bz.y = p0.y; bz.z = p1.x; bz.w = p1.y;
    } else if (g == 2) bz.x = (__fp16)1.f;

    // ---- FFN: one tile, 32 chunks ----
    float4v acc = zero4;
    #pragma unroll 4
    for (int nf = 0; nf < 32; ++nf) {
        half4 a1f = a1l[nf * 64 + l];
        half4 a2f = a2l[nf * 64 + l];
        float4v d = __builtin_amdgcn_mfma_f32_16x16x16f16(a1f, bz, zero4, 0, 0, 0);
        half2v p0 = __builtin_amdgcn_cvt_pkrtz(d[0], d[1]);
        half2v p1 = __builtin_amdgcn_cvt_pkrtz(d[2], d[3]);
        half4 bu; bu.x = p0.x; bu.y = p0.y; bu.z = p1.x; bu.w = p1.y;
        bu = __builtin_elementwise_max(bu, zh);
        acc = __builtin_amdgcn_mfma_f32_16x16x16f16(a2f, bu, acc, 0, 0, 0);
    }

    // ---- residual + LN2 + store (lanes g<2) ----
    if (g < 2) {
        const float4 lb4 = *reinterpret_cast<const float4*>(&wl[O_L2B + k0]);
        const float4 g24 = *reinterpret_cast<const float4*>(&wl[O_G2 + k0]);
        const float4 b24 = *reinterpret_cast<const float4*>(&wl[O_B2 + k0]);
        float r20 = hh0 + acc[0] + lb4.x;
        float r21 = hh1 + acc[1] + lb4.y;
        float r22 = hh2 + acc[2] + lb4.z;
        float r23 = hh3 + acc[3] + lb4.w;
        float part = (r20 + r21) + (r22 + r23);
        float mean2 = (part + SWZ16(part)) * 0.125f;
        float e0 = r20 - mean2, e1 = r21 - mean2, e2 = r22 - mean2, e3 = r23 - mean2;
        float vp = (e0 * e0 + e1 * e1) + (e2 * e2 + e3 * e3);
        float rs2 = __builtin_amdgcn_rsqf((vp + SWZ16(vp)) * 0.125f + 1e-5f);
        float4 o;
        o.x = fmaf(e0 * rs2, g24.x, b24.x);
        o.y = fmaf(e1 * rs2, g24.y, b24.y);
        o.z = fmaf(e2 * rs2, g24.z, b24.z);
        o.w = fmaf(e3 * rs2, g24.w, b24.w);
        *reinterpret_cast<float4*>(out + (gtok + n) * 8 + k0) = o;
    }
}

extern "C" void kernel_launch(void* const* d_in, const int* in_sizes, int n_in,
                              void* d_out, int out_size, void* d_ws, size_t ws_size,
                              hipStream_t stream) {
    const float* x   = (const float*)d_in[0];
    const float* ipw = (const float*)d_in[1];
    const float* ipb = (const float*)d_in[2];
    const float* opw = (const float*)d_in[3];
    const float* opb = (const float*)d_in[4];
    const float* rxa = (const float*)d_in[5];
    const float* cw  = (const float*)d_in[6];
    const float* cb  = (const float*)d_in[7];
    const float* g1  = (const float*)d_in[8];
    const float* b1  = (const float*)d_in[9];
    const float* rxf = (const float*)d_in[10];
    const float* l1w = (const float*)d_in[11];
    const float* l1b = (const float*)d_in[12];
    const float* l2w = (const float*)d_in[13];
    const float* l2b = (const float*)d_in[14];
    const float* g2  = (const float*)d_in[15];
    const float* b2  = (const float*)d_in[16];
    float* out = (float*)d_out;

    const int tokens = 16384 * 8;               // 131072
    tbq_fused<<<dim3(tokens / 128), dim3(512), 0, stream>>>(
        x, ipw, ipb, opw, opb, rxa, cw, cb, g1, b1, rxf,
        l1w, l1b, l2w, l2b, g2, b2, out);
}